// Round 1
// baseline (126.967 us; speedup 1.0000x reference)
//
#include <hip/hip_runtime.h>

// Cost-volume block: f1n = l2norm_C(f1); hori/verti 9-offset correlations vs f2,
// mean over C, leaky_relu(0.01), concat -> [B, 18, H, W].
// Shapes fixed by setup_inputs: B=256, C=64, H=W=64, sr=4.

constexpr int SR    = 4;
constexpr int NOFF  = 2 * SR + 1;   // 9
constexpr int Bb    = 256;
constexpr int Cc    = 64;
constexpr int Hh    = 64;
constexpr int Ww    = 64;
constexpr int BH    = 16;                // h rows per block
constexpr int BAND  = BH + 2 * SR;       // 24 staged f2 rows
constexpr int RP    = Ww + 2 * SR;       // 72 padded row stride (zeros at both ends)
constexpr int CCH   = 4;                 // channels staged per chunk
constexpr int NCHUNK = Cc / CCH;         // 16
constexpr int GR_PER_CH = BAND * (Ww / 4);   // 384 granules (float4) per channel
constexpr int GR_TOTAL  = CCH * GR_PER_CH;   // 1536
constexpr int GR_PER_T  = GR_TOTAL / 256;    // 6

__device__ __forceinline__ float lrelu(float x) {
    // leaky relu slope 0.01:  max(x, 0.01x) is exact for both signs
    return fmaxf(x, 0.01f * x);
}

__global__ __launch_bounds__(256)
void cv_kernel(const float* __restrict__ f1, const float* __restrict__ f2,
               float* __restrict__ out)
{
    __shared__ float lds[CCH][BAND][RP];   // 4*24*72*4B = 27648 B

    const int t  = threadIdx.x;
    const int tx = t & 15;          // w-granule (4 floats each)
    const int ty = t >> 4;          // h row within tile
    const int b  = blockIdx.x;
    const int h0 = blockIdx.y * BH;
    const int h  = h0 + ty;

    // Zero the horizontal pad granules once; staging never overwrites them.
    if (t < CCH * BAND * 2) {
        const int cr = t >> 1, side = t & 1;
        const int c = cr / BAND, r = cr % BAND;
        *reinterpret_cast<float4*>(&lds[c][r][side ? (RP - 4) : 0]) =
            make_float4(0.f, 0.f, 0.f, 0.f);
    }

    float hacc[NOFF][4];
    float vacc[NOFF][4];
    float nsq[4];
#pragma unroll
    for (int d = 0; d < NOFF; ++d)
#pragma unroll
        for (int q = 0; q < 4; ++q) { hacc[d][q] = 0.f; vacc[d][q] = 0.f; }
#pragma unroll
    for (int q = 0; q < 4; ++q) nsq[q] = 0.f;

    const float* f1p    = f1 + (((size_t)b * Cc) * Hh + h) * Ww + 4 * tx;
    const float* f2base = f2 + ((size_t)b * Cc) * (size_t)(Hh * Ww);

    for (int cc = 0; cc < NCHUNK; ++cc) {
        const int c0 = cc * CCH;

        // ---- gather phase (global loads only; overlaps previous compute) ----
        float4 sv[GR_PER_T];
        int    c_of[GR_PER_T], r_of[GR_PER_T], g_of[GR_PER_T];
#pragma unroll
        for (int k = 0; k < GR_PER_T; ++k) {
            const int g   = t + 256 * k;
            const int c   = g / GR_PER_CH;
            const int rem = g - c * GR_PER_CH;
            const int r   = rem >> 4;
            const int gc  = rem & 15;
            c_of[k] = c; r_of[k] = r; g_of[k] = gc;
            const int row = h0 - SR + r;
            if (row >= 0 && row < Hh) {
                sv[k] = *reinterpret_cast<const float4*>(
                    f2base + ((size_t)(c0 + c) * Hh + row) * Ww + 4 * gc);
            } else {
                sv[k] = make_float4(0.f, 0.f, 0.f, 0.f);
            }
        }
        // f1 prefetch for this chunk (latency hidden by the barrier)
        float4 a[CCH];
#pragma unroll
        for (int c = 0; c < CCH; ++c)
            a[c] = *reinterpret_cast<const float4*>(f1p + (size_t)(c0 + c) * (Hh * Ww));

        __syncthreads();   // previous chunk's compute done -> safe to overwrite LDS
#pragma unroll
        for (int k = 0; k < GR_PER_T; ++k)
            *reinterpret_cast<float4*>(&lds[c_of[k]][r_of[k]][SR + 4 * g_of[k]]) = sv[k];
        __syncthreads();   // staged data visible

        // ---- compute phase ----
#pragma unroll
        for (int c = 0; c < CCH; ++c) {
            const float4 av = a[c];
            nsq[0] += av.x * av.x;
            nsq[1] += av.y * av.y;
            nsq[2] += av.z * av.z;
            nsq[3] += av.w * av.w;

            // horizontal window: padded floats [4tx .. 4tx+11] == w in [4tx-4, 4tx+7]
            float win[12];
            *reinterpret_cast<float4*>(&win[0]) =
                *reinterpret_cast<const float4*>(&lds[c][ty + SR][4 * tx]);
            *reinterpret_cast<float4*>(&win[4]) =
                *reinterpret_cast<const float4*>(&lds[c][ty + SR][4 * tx + 4]);
            *reinterpret_cast<float4*>(&win[8]) =
                *reinterpret_cast<const float4*>(&lds[c][ty + SR][4 * tx + 8]);
#pragma unroll
            for (int d = 0; d < NOFF; ++d) {
                hacc[d][0] += av.x * win[0 + d];
                hacc[d][1] += av.y * win[1 + d];
                hacc[d][2] += av.z * win[2 + d];
                hacc[d][3] += av.w * win[3 + d];
            }
            // vertical: band row ty+d corresponds to h + (d - SR)
#pragma unroll
            for (int d = 0; d < NOFF; ++d) {
                const float4 v = *reinterpret_cast<const float4*>(
                    &lds[c][ty + d][SR + 4 * tx]);
                vacc[d][0] += av.x * v.x;
                vacc[d][1] += av.y * v.y;
                vacc[d][2] += av.z * v.z;
                vacc[d][3] += av.w * v.w;
            }
        }
        __syncthreads();   // compute done before next chunk's staging
    }

    // ---- epilogue: scale by 1/(C * max(||f1||, eps)), leaky relu, store ----
    float sc[4];
#pragma unroll
    for (int q = 0; q < 4; ++q)
        sc[q] = 1.0f / (64.0f * fmaxf(sqrtf(nsq[q]), 1e-12f));

    float* op = out + (((size_t)b * (2 * NOFF)) * Hh + h) * Ww + 4 * tx;
#pragma unroll
    for (int d = 0; d < NOFF; ++d) {
        float4 o;
        o.x = lrelu(hacc[d][0] * sc[0]);
        o.y = lrelu(hacc[d][1] * sc[1]);
        o.z = lrelu(hacc[d][2] * sc[2]);
        o.w = lrelu(hacc[d][3] * sc[3]);
        *reinterpret_cast<float4*>(op + (size_t)d * Hh * Ww) = o;
    }
#pragma unroll
    for (int d = 0; d < NOFF; ++d) {
        float4 o;
        o.x = lrelu(vacc[d][0] * sc[0]);
        o.y = lrelu(vacc[d][1] * sc[1]);
        o.z = lrelu(vacc[d][2] * sc[2]);
        o.w = lrelu(vacc[d][3] * sc[3]);
        *reinterpret_cast<float4*>(op + (size_t)(NOFF + d) * Hh * Ww) = o;
    }
}

extern "C" void kernel_launch(void* const* d_in, const int* in_sizes, int n_in,
                              void* d_out, int out_size, void* d_ws, size_t ws_size,
                              hipStream_t stream) {
    const float* f1 = (const float*)d_in[0];
    const float* f2 = (const float*)d_in[1];
    float* out = (float*)d_out;
    dim3 grid(Bb, Hh / BH);   // 256 x 4 = 1024 blocks
    cv_kernel<<<grid, dim3(256), 0, stream>>>(f1, f2, out);
}